// Round 9
// baseline (252.620 us; speedup 1.0000x reference)
//
#include <hip/hip_runtime.h>
#include <hip/hip_bf16.h>
#include <math.h>

typedef unsigned short u16;
typedef unsigned int   u32;
typedef __attribute__((ext_vector_type(8))) short bf16x8;
typedef __attribute__((ext_vector_type(4))) float f32x4;
typedef __attribute__((ext_vector_type(4))) unsigned short u16x4;
typedef __attribute__((ext_vector_type(4))) unsigned int   u32x4;

#define T_SEQ 2048
#define BATCH 2
#define NHEAD 16
#define KVHEADS 4
#define HD 128
#define DM 2048
#define QKV_N 3072
#define MROWS 4096

__device__ __forceinline__ float bf2f(u16 u) {
    union { u32 i; float f; } v; v.i = ((u32)u) << 16; return v.f;
}
__device__ __forceinline__ u16 f2bf(float f) {
    u32 x = __float_as_uint(f);
    u32 r = (x + 0x7fffu + ((x >> 16) & 1u)) >> 16;
    return (u16)r;
}

// async global->LDS, 16B per lane; dest = wave-uniform base + lane*16
__device__ __forceinline__ void gl16(const void* g, void* lds) {
    __builtin_amdgcn_global_load_lds(
        (const __attribute__((address_space(1))) void*)g,
        (__attribute__((address_space(3))) void*)lds, 16, 0, 0);
}

__device__ __forceinline__ int alibi_w1(int h) {
    // W1 = floor(36 * 2^((h+1)/2) / 64) + 2 ; beyond this many 64-tiles the
    // ALiBi bias alone makes contributions < e^-36 relative (exact drop).
    return (int)(36.0f * exp2f(0.5f * (float)(h + 1)) * (1.0f / 64.0f)) + 2;
}

// ---------------------------------------------------------------------------
__global__ void reset_u32(u32* p, u32 v) { *p = v; }

// ---------------------------------------------------------------------------
__global__ void cvt_f32_bf16(const float* __restrict__ in, u16* __restrict__ out, int nq)
{
    int i = blockIdx.x * blockDim.x + threadIdx.x;
    const int stride = gridDim.x * blockDim.x;
    for (; i < nq; i += stride) {
        f32x4 v = ((const f32x4*)in)[i];
        u16x4 o = { f2bf(v[0]), f2bf(v[1]), f2bf(v[2]), f2bf(v[3]) };
        ((u16x4*)out)[i] = o;
    }
}

// ---------------------------------------------------------------------------
// GEMM (unchanged from r8): 128x128 tile, BK=64, global_load_lds staging.
// ---------------------------------------------------------------------------
template <int EPI>
__global__ __launch_bounds__(256, 3)
void gemm_bt(const u16* __restrict__ A, const u16* __restrict__ Bw,
             const float* __restrict__ bias, u16* __restrict__ C,
             float* __restrict__ Cf, u16* __restrict__ Vt, int M, int N, int K)
{
    __shared__ __align__(16) u16 As[128 * 64];
    __shared__ __align__(16) u16 Bs[128 * 64];

    const int tid = threadIdx.x;
    const int l = tid & 63;
    const int w = tid >> 6;
    const int wr = w >> 1, wc = w & 1;
    const int bm = blockIdx.x, bn = blockIdx.y;

    const int lrow = l >> 3;
    const int lsl  = (l & 7) ^ lrow;
    const size_t aBase = (size_t)(bm * 128 + w * 8 + lrow) * K + lsl * 8;
    const size_t bBase = (size_t)(bn * 128 + w * 8 + lrow) * K + lsl * 8;

    const int sw = (l & 7) << 4;
    int offA[4], offB[4];
#pragma unroll
    for (int mf = 0; mf < 4; ++mf)
        offA[mf] = (wr * 64 + mf * 16 + (l & 15)) * 128 + (((l >> 4) * 16) ^ sw);
#pragma unroll
    for (int nf = 0; nf < 4; ++nf)
        offB[nf] = (wc * 64 + nf * 16 + (l & 15)) * 128 + (((l >> 4) * 16) ^ sw);

    f32x4 acc[4][4];
#pragma unroll
    for (int i = 0; i < 4; ++i)
#pragma unroll
        for (int j = 0; j < 4; ++j)
            acc[i][j] = (f32x4){0.f, 0.f, 0.f, 0.f};

    const int nK = K >> 6;
    for (int kt = 0; kt < nK; ++kt) {
        __syncthreads();
#pragma unroll
        for (int j = 0; j < 4; ++j) {
            gl16(A  + aBase + (size_t)j * 32 * K + kt * 64,
                 (char*)As + (w * 8 + j * 32) * 128);
            gl16(Bw + bBase + (size_t)j * 32 * K + kt * 64,
                 (char*)Bs + (w * 8 + j * 32) * 128);
        }
        __syncthreads();
#pragma unroll
        for (int kk = 0; kk < 2; ++kk) {
            bf16x8 af[4], bfr[4];
#pragma unroll
            for (int mf = 0; mf < 4; ++mf)
                af[mf] = *(const bf16x8*)((const char*)As + (offA[mf] ^ (kk << 6)));
#pragma unroll
            for (int nf = 0; nf < 4; ++nf)
                bfr[nf] = *(const bf16x8*)((const char*)Bs + (offB[nf] ^ (kk << 6)));
            __builtin_amdgcn_s_setprio(1);
#pragma unroll
            for (int mf = 0; mf < 4; ++mf)
#pragma unroll
                for (int nf = 0; nf < 4; ++nf)
                    acc[mf][nf] = __builtin_amdgcn_mfma_f32_16x16x32_bf16(
                        af[mf], bfr[nf], acc[mf][nf], 0, 0, 0);
            __builtin_amdgcn_s_setprio(0);
        }
    }

    const int row0 = bm * 128 + wr * 64 + ((l >> 4) << 2);
    const int col0 = bn * 128 + wc * 64 + (l & 15);
#pragma unroll
    for (int mf = 0; mf < 4; ++mf) {
#pragma unroll
        for (int nf = 0; nf < 4; ++nf) {
            const int row = row0 + mf * 16;
            const int col = col0 + nf * 16;
            const float bv = bias[col];
            float v0 = acc[mf][nf][0] + bv;
            float v1 = acc[mf][nf][1] + bv;
            float v2 = acc[mf][nf][2] + bv;
            float v3 = acc[mf][nf][3] + bv;
            if (EPI == 0) {
                if (col < 2560) {
                    C[(size_t)(row + 0) * QKV_N + col] = f2bf(v0);
                    C[(size_t)(row + 1) * QKV_N + col] = f2bf(v1);
                    C[(size_t)(row + 2) * QKV_N + col] = f2bf(v2);
                    C[(size_t)(row + 3) * QKV_N + col] = f2bf(v3);
                } else {
                    const int dd = col - 2560;
                    const int kv = dd >> 7;
                    const int d = dd & 127;
                    const int bidx = row >> 11;
                    const int tt = row & 2047;
                    u16x4 pv = {f2bf(v0), f2bf(v1), f2bf(v2), f2bf(v3)};
                    *(u16x4*)(Vt + ((size_t)((bidx * KVHEADS + kv) * HD + d)) * T_SEQ + tt) = pv;
                }
            } else {
                Cf[(size_t)(row + 0) * DM + col] = v0;
                Cf[(size_t)(row + 1) * DM + col] = v1;
                Cf[(size_t)(row + 2) * DM + col] = v2;
                Cf[(size_t)(row + 3) * DM + col] = v3;
            }
        }
    }
}

// ---------------------------------------------------------------------------
// Flash attention v7: QBLK=128 (4 waves x 32 q-rows, 2 M-frags/wave).
// K/V fragment reads amortized 2x; staging/barriers per unit of work halved.
// Work queue: 512 static items (b,h,qt2), qt2 descending; seg1 of split items
// popped via atomic. Split = balanced halves when ntiles >= 20.
// Reverse s-iteration + ALiBi window + shuffle-free defer-max + l via
// ones-MFMA. K/V double-buffered LDS, one barrier per s-tile.
// PWS per seg: [128][128] O + m[128] + l[128] = 16640 floats.
// ---------------------------------------------------------------------------
#define PWS_SEG2 16640
__global__ __launch_bounds__(256, 2)
void attn_fwd(const u16* __restrict__ qkv, const u16* __restrict__ Vt,
              u16* __restrict__ AO, u32* __restrict__ ctr,
              float* __restrict__ PWS)
{
    __shared__ __align__(16) u16 Ks[2 * 64 * 128];   // 2 x 16KB
    __shared__ __align__(16) u16 Vs[2 * 64 * 128];   // 2 x 16KB [d][s]
    __shared__ __align__(16) u16 Ps[4 * 32 * 64];    // per-wave P, 16KB
    __shared__ int sh_item;

    const int tid = threadIdx.x;
    const int l = tid & 63;
    const int w = tid >> 6;

    const int sw = (l & 7) << 4;
    int offK0[4], offV0[8];
#pragma unroll
    for (int nf = 0; nf < 4; ++nf)
        offK0[nf] = (nf * 16 + (l & 15)) * 256 + (((l >> 4) * 16) ^ sw);
#pragma unroll
    for (int nf = 0; nf < 8; ++nf)
        offV0[nf] = (nf * 16 + (l & 15)) * 128 + (((l >> 4) * 16) ^ sw);

    const int rk = tid >> 4, skk = tid & 15;
    const int loK = rk * 256 + ((skk * 16) ^ ((rk & 7) << 4));
    const int rv = tid >> 3, svv = tid & 7;
    const int loV = rv * 128 + ((svv * 16) ^ ((rv & 7) << 4));

    const float LOG2E = 1.4426950408889634f;
    const float scale2 = 0.08838834764831845f * LOG2E;
    const bf16x8 ones = {(short)0x3F80, (short)0x3F80, (short)0x3F80, (short)0x3F80,
                         (short)0x3F80, (short)0x3F80, (short)0x3F80, (short)0x3F80};

    int item = blockIdx.x;   // static first item

    for (;;) {
        __syncthreads();     // prior item's LDS reads done; sh_item reusable
        if (item < 0 && tid == 0) sh_item = (int)atomicAdd(ctr, 1u);
        __syncthreads();
        if (item < 0) item = sh_item;
        if (item >= 1024) break;

        const int seg = (item < 512) ? 0 : 1;
        const int idx = (item < 512) ? item : item - 512;
        const int qt2 = 15 - (idx >> 5);
        const int bh = idx & 31;
        const int b = bh >> 4;
        const int h = bh & 15;
        const int kvh = h >> 2;
        const int q0 = qt2 << 7;

        const float slope2 = exp2f(-0.5f * (float)(h + 1)) * LOG2E;
        const int W1 = alibi_w1(h);
        const int jt_min = (2 * qt2 - W1 > 0) ? (2 * qt2 - W1) : 0;
        const int ntiles = 2 * qt2 + 2 - jt_min;
        const bool split = (ntiles >= 20);
        if (seg == 1 && !split) { item = -1; continue; }

        int jt_hi, jt_lo;
        if (!split)        { jt_hi = 2 * qt2 + 1;          jt_lo = jt_min; }
        else if (seg == 0) { jt_hi = 2 * qt2 + 1;          jt_lo = jt_min + (ntiles >> 1); }
        else               { jt_hi = jt_min + (ntiles >> 1) - 1; jt_lo = jt_min; }

        const size_t gK0 = (size_t)(b * T_SEQ + rk) * QKV_N + 2048 + kvh * HD + skk * 8;
        const size_t gV0 = (size_t)((b * KVHEADS + kvh) * HD + rv) * T_SEQ + svv * 8;

        // Q fragments: wave rows = q0 + w*32 + mf*16 + (l&15)
        bf16x8 qreg[2][4];
#pragma unroll
        for (int mf = 0; mf < 2; ++mf)
#pragma unroll
            for (int kk = 0; kk < 4; ++kk)
                qreg[mf][kk] = *(const bf16x8*)(qkv +
                    (size_t)(b * T_SEQ + q0 + w * 32 + mf * 16 + (l & 15)) * QKV_N +
                    (size_t)h * HD + kk * 32 + ((l >> 4) << 3));

        float m_run[2][4];
        f32x4 o[2][8];
        f32x4 lacc[2] = {(f32x4){0.f,0.f,0.f,0.f}, (f32x4){0.f,0.f,0.f,0.f}};
#pragma unroll
        for (int mf = 0; mf < 2; ++mf) {
#pragma unroll
            for (int i = 0; i < 4; ++i) m_run[mf][i] = -1e30f;
#pragma unroll
            for (int nf = 0; nf < 8; ++nf) o[mf][nf] = (f32x4){0.f, 0.f, 0.f, 0.f};
        }

        // ALiBi decomposition: bias(mf,nf,i) = rowoff[mf][i] + coloff[nf]
        const float dslope = slope2 * 64.0f;
        float rowoff[2][4], coloff[4];
#pragma unroll
        for (int mf = 0; mf < 2; ++mf)
#pragma unroll
            for (int i = 0; i < 4; ++i)
                rowoff[mf][i] = slope2 * (float)((jt_hi << 6) + (l & 15)
                                - (q0 + w * 32 + mf * 16 + ((l >> 4) << 2) + i));
#pragma unroll
        for (int nf = 0; nf < 4; ++nf) coloff[nf] = slope2 * (float)(nf * 16);

        // prologue: tile jt_hi -> regs -> buffer 0
        u32x4 pk[4], pv[4];
#pragma unroll
        for (int j = 0; j < 4; ++j) {
            pk[j] = *(const u32x4*)(qkv + gK0 + (size_t)((jt_hi << 6) + j * 16) * QKV_N);
            pv[j] = *(const u32x4*)(Vt + gV0 + (jt_hi << 6) + (size_t)j * 32 * T_SEQ);
        }
#pragma unroll
        for (int j = 0; j < 4; ++j) {
            *(u32x4*)((char*)Ks + loK + j * 16 * 256) = pk[j];
            *(u32x4*)((char*)Vs + loV + j * 32 * 128) = pv[j];
        }

        for (int c = 0, jt = jt_hi; jt >= jt_lo; --jt, ++c) {
            const int bsel = (c & 1) << 14;

            __syncthreads();   // buf[c&1] staged; frees buf[(c+1)&1]

            if (jt > jt_lo) {
                const int ns0 = (jt - 1) << 6;
#pragma unroll
                for (int j = 0; j < 4; ++j) {
                    pk[j] = *(const u32x4*)(qkv + gK0 + (size_t)(ns0 + j * 16) * QKV_N);
                    pv[j] = *(const u32x4*)(Vt + gV0 + ns0 + (size_t)j * 32 * T_SEQ);
                }
            }

            // diagonal-tile wave roles: c==0 (jt=2qt2+1): waves 0,1 fully
            // masked -> skip; waves 2,3 partial mask. c==1 (jt=2qt2): waves
            // 0,1 partial mask; waves 2,3 unmasked.
            const bool skipw = (seg == 0 && c == 0 && w < 2);
            if (!skipw) {
                // ---- S = Q K^T (32 rows x 64 cols per wave) ----
                f32x4 sc[2][4];
#pragma unroll
                for (int mf = 0; mf < 2; ++mf)
#pragma unroll
                    for (int nf = 0; nf < 4; ++nf) sc[mf][nf] = (f32x4){0.f,0.f,0.f,0.f};
                __builtin_amdgcn_s_setprio(1);
#pragma unroll
                for (int kk = 0; kk < 4; ++kk) {
#pragma unroll
                    for (int nf = 0; nf < 4; ++nf) {
                        bf16x8 kb = *(const bf16x8*)((const char*)Ks + bsel + (offK0[nf] ^ (kk << 6)));
                        sc[0][nf] = __builtin_amdgcn_mfma_f32_16x16x32_bf16(qreg[0][kk], kb, sc[0][nf], 0, 0, 0);
                        sc[1][nf] = __builtin_amdgcn_mfma_f32_16x16x32_bf16(qreg[1][kk], kb, sc[1][nf], 0, 0, 0);
                    }
                }
                __builtin_amdgcn_s_setprio(0);

                // ---- vals = sc*scale2 + alibi (log2 domain) ----
                float vals[2][4][4];
#pragma unroll
                for (int mf = 0; mf < 2; ++mf)
#pragma unroll
                    for (int nf = 0; nf < 4; ++nf)
#pragma unroll
                        for (int i = 0; i < 4; ++i)
                            vals[mf][nf][i] = fmaf(sc[mf][nf][i], scale2,
                                                   rowoff[mf][i] + coloff[nf]);
                if (seg == 0 && c < 2) {
                    const bool needmask = (c == 0) ? (w >= 2) : (w < 2);
                    if (needmask) {
                        const int s0i = jt << 6;
#pragma unroll
                        for (int mf = 0; mf < 2; ++mf)
#pragma unroll
                            for (int nf = 0; nf < 4; ++nf) {
                                const int scol = s0i + nf * 16 + (l & 15);
#pragma unroll
                                for (int i = 0; i < 4; ++i) {
                                    const int trow = q0 + w * 32 + mf * 16 + ((l >> 4) << 2) + i;
                                    if (scol > trow) vals[mf][nf][i] = -__builtin_inff();
                                }
                            }
                    }
                }

                // ---- shuffle-free defer-max ----
                float lm[2][4];
                bool ok = true;
#pragma unroll
                for (int mf = 0; mf < 2; ++mf)
#pragma unroll
                    for (int i = 0; i < 4; ++i) {
                        lm[mf][i] = fmaxf(fmaxf(vals[mf][0][i], vals[mf][1][i]),
                                          fmaxf(vals[mf][2][i], vals[mf][3][i]));
                        ok = ok && (lm[mf][i] <= m_run[mf][i] + 10.f);
                    }
                if (!__all(ok)) {
                    float corr[2][4];
#pragma unroll
                    for (int mf = 0; mf < 2; ++mf)
#pragma unroll
                        for (int i = 0; i < 4; ++i) {
                            float mx = lm[mf][i];
#pragma unroll
                            for (int d = 1; d < 16; d <<= 1) mx = fmaxf(mx, __shfl_xor(mx, d, 64));
                            const float mn = fmaxf(m_run[mf][i], mx);
                            corr[mf][i] = exp2f(m_run[mf][i] - mn);
                            m_run[mf][i] = mn;
                        }
#pragma unroll
                    for (int mf = 0; mf < 2; ++mf) {
#pragma unroll
                        for (int nf = 0; nf < 8; ++nf) {
                            o[mf][nf][0] *= corr[mf][0]; o[mf][nf][1] *= corr[mf][1];
                            o[mf][nf][2] *= corr[mf][2]; o[mf][nf][3] *= corr[mf][3];
                        }
                        lacc[mf][0] *= corr[mf][0]; lacc[mf][1] *= corr[mf][1];
                        lacc[mf][2] *= corr[mf][2]; lacc[mf][3] *= corr[mf][3];
                    }
                }

                // ---- P = exp2(vals - m) -> per-wave LDS ----
                const int pbase = w * 4096;
#pragma unroll
                for (int mf = 0; mf < 2; ++mf)
#pragma unroll
                    for (int nf = 0; nf < 4; ++nf)
#pragma unroll
                        for (int i = 0; i < 4; ++i) {
                            const float p = exp2f(vals[mf][nf][i] - m_run[mf][i]);
                            const int r = mf * 16 + ((l >> 4) << 2) + i;
                            const int off = pbase + ((r * 128 + nf * 32 + ((l & 15) << 1))
                                            ^ ((r & 7) << 4));
                            *(u16*)((char*)Ps + off) = f2bf(p);
                        }

                // ---- O += P @ V ; lacc += P @ ones ----
                __builtin_amdgcn_s_setprio(1);
#pragma unroll
                for (int kk = 0; kk < 2; ++kk) {
                    bf16x8 pfr[2];
#pragma unroll
                    for (int mf = 0; mf < 2; ++mf) {
                        const int rp = mf * 16 + (l & 15);
                        pfr[mf] = *(const bf16x8*)((const char*)Ps + pbase +
                                   (rp * 128 + ((((l >> 4) * 16) ^ sw) ^ (kk << 6))));
                        lacc[mf] = __builtin_amdgcn_mfma_f32_16x16x32_bf16(pfr[mf], ones, lacc[mf], 0, 0, 0);
                    }
#pragma unroll
                    for (int nf = 0; nf < 8; ++nf) {
                        bf16x8 vb = *(const bf16x8*)((const char*)Vs + bsel + (offV0[nf] ^ (kk << 6)));
                        o[0][nf] = __builtin_amdgcn_mfma_f32_16x16x32_bf16(pfr[0], vb, o[0][nf], 0, 0, 0);
                        o[1][nf] = __builtin_amdgcn_mfma_f32_16x16x32_bf16(pfr[1], vb, o[1][nf], 0, 0, 0);
                    }
                }
                __builtin_amdgcn_s_setprio(0);
            }

            // rowoff advance (all waves, incl. skipped)
#pragma unroll
            for (int mf = 0; mf < 2; ++mf)
#pragma unroll
                for (int i = 0; i < 4; ++i) rowoff[mf][i] -= dslope;

            // ---- publish tile jt-1 into the other buffer ----
            if (jt > jt_lo) {
                const int b2 = ((c + 1) & 1) << 14;
#pragma unroll
                for (int j = 0; j < 4; ++j) {
                    *(u32x4*)((char*)Ks + b2 + loK + j * 16 * 256) = pk[j];
                    *(u32x4*)((char*)Vs + b2 + loV + j * 32 * 128) = pv[j];
                }
            }
        }

        // ---- epilogue ----
        if (!split) {
#pragma unroll
            for (int mf = 0; mf < 2; ++mf) {
                float rinv[4];
#pragma unroll
                for (int i = 0; i < 4; ++i) rinv[i] = 1.f / lacc[mf][i];
                const size_t orow = (size_t)(b * T_SEQ + q0 + w * 32 + mf * 16 + ((l >> 4) << 2));
#pragma unroll
                for (int nf = 0; nf < 8; ++nf) {
                    const int col = h * HD + nf * 16 + (l & 15);
#pragma unroll
                    for (int i = 0; i < 4; ++i)
                        AO[(orow + i) * DM + col] = f2bf(o[mf][nf][i] * rinv[i]);
                }
            }
        } else {
            const int rid = (bh << 4) | qt2;
            float* base = PWS + (size_t)(rid * 2 + seg) * PWS_SEG2;
#pragma unroll
            for (int mf = 0; mf < 2; ++mf) {
                const int row0 = w * 32 + mf * 16 + ((l >> 4) << 2);
#pragma unroll
                for (int nf = 0; nf < 8; ++nf) {
                    const int col = nf * 16 + (l & 15);
#pragma unroll
                    for (int i = 0; i < 4; ++i)
                        base[(row0 + i) * 128 + col] = o[mf][nf][i];
                }
                if ((l & 15) == 0) {
#pragma unroll
                    for (int i = 0; i < 4; ++i) {
                        base[16384 + row0 + i] = m_run[mf][i];
                        base[16512 + row0 + i] = lacc[mf][i];
                    }
                }
            }
        }

        item = -1;   // pop next from queue
    }
}

// ---------------------------------------------------------------------------
// Combine split items: AO = (O0*w0 + O1*w1) / (l0*w0 + l1*w1)
// ---------------------------------------------------------------------------
__global__ __launch_bounds__(256)
void attn_combine(const float* __restrict__ PWS, u16* __restrict__ AO)
{
    const int rid = blockIdx.x;          // (bh<<4)|qt2
    const int qt2 = rid & 15;
    const int bh = rid >> 4;
    const int b = bh >> 4;
    const int h = bh & 15;
    const int W1 = alibi_w1(h);
    const int jt_min = (2 * qt2 - W1 > 0) ? (2 * qt2 - W1) : 0;
    if (2 * qt2 + 2 - jt_min < 20) return;   // not split

    const float* p0 = PWS + (size_t)(rid * 2 + 0) * PWS_SEG2;
    const float* p1 = PWS + (size_t)(rid * 2 + 1) * PWS_SEG2;

    const int t = threadIdx.x;
    const int row = t >> 1;
    const int c0 = (t & 1) * 64;

    const float m0 = p0[16384 + row], m1 = p1[16384 + row];
    const float l0 = p0[16512 + row], l1 = p1[16512 + row];
    const float m = fmaxf(m0, m1);
    const float w0 = exp2f(m0 - m), w1 = exp2f(m1 - m);
    const float rinv = 1.f / (l0 * w0 + l1 * w1);

    const size_t ao = (size_t)(b * T_SEQ + (qt2 << 7) + row) * DM + h * HD + c0;
#pragma unroll
    for (int j = 0; j < 64; j += 4) {
        f32x4 a = *(const f32x4*)(p0 + row * 128 + c0 + j);
        f32x4 bx = *(const f32x4*)(p1 + row * 128 + c0 + j);
#pragma unroll
        for (int q = 0; q < 4; ++q)
            AO[ao + j + q] = f2bf((a[q] * w0 + bx[q] * w1) * rinv);
    }
}

// ---------------------------------------------------------------------------
extern "C" void kernel_launch(void* const* d_in, const int* in_sizes, int n_in,
                              void* d_out, int out_size, void* d_ws, size_t ws_size,
                              hipStream_t stream)
{
    const float* x      = (const float*)d_in[0];
    // d_in[1] = attn_mask (causal, analytic)
    // d_in[2] = alibi_bias (analytic)
    const float* qkv_w  = (const float*)d_in[3];
    const float* qkv_b  = (const float*)d_in[4];
    const float* proj_w = (const float*)d_in[5];
    const float* proj_b = (const float*)d_in[6];
    float* out = (float*)d_out;

    u16* ws  = (u16*)d_ws;
    u16* xb  = ws;                                   // 4096*2048
    u16* AO  = ws;                                   // alias: x dead after gemm0
    u16* qwb = ws + 8388608;                         // 3072*2048
    u16* pwb = qwb + 6291456;                        // 2048*2048
    u16* qkv = pwb + 4194304;                        // 4096*3072
    u16* Vt  = qkv + 12582912;                       // 2*4*128*2048
    u32* ctr = (u32*)(ws + 33554432);                // queue counter (4B)
    float* PWS = (float*)((char*)d_ws + 67108880);   // split partials ~68MB

    reset_u32<<<1, 1, 0, stream>>>(ctr, 512u);
    cvt_f32_bf16<<<2048, 256, 0, stream>>>(x,      xb,  8388608 / 4);
    cvt_f32_bf16<<<2048, 256, 0, stream>>>(qkv_w,  qwb, 6291456 / 4);
    cvt_f32_bf16<<<1024, 256, 0, stream>>>(proj_w, pwb, 4194304 / 4);

    gemm_bt<0><<<dim3(32, 24), 256, 0, stream>>>(xb, qwb, qkv_b, qkv, nullptr, Vt,
                                                 MROWS, QKV_N, DM);
    attn_fwd<<<dim3(512), 256, 0, stream>>>(qkv, Vt, AO, ctr, PWS);
    attn_combine<<<dim3(512), 256, 0, stream>>>(PWS, AO);
    gemm_bt<1><<<dim3(32, 16), 256, 0, stream>>>(AO, pwb, proj_b, nullptr, out, nullptr,
                                                 MROWS, DM, DM);
}

// Round 11
// 193.555 us; speedup vs baseline: 1.3052x; 1.3052x over previous
//
#include <hip/hip_runtime.h>
#include <hip/hip_bf16.h>
#include <math.h>

typedef unsigned short u16;
typedef unsigned int   u32;
typedef __attribute__((ext_vector_type(8))) short bf16x8;
typedef __attribute__((ext_vector_type(4))) float f32x4;
typedef __attribute__((ext_vector_type(4))) unsigned short u16x4;
typedef __attribute__((ext_vector_type(4))) unsigned int   u32x4;

#define T_SEQ 2048
#define BATCH 2
#define NHEAD 16
#define KVHEADS 4
#define HD 128
#define DM 2048
#define QKV_N 3072
#define MROWS 4096

__device__ __forceinline__ float bf2f(u16 u) {
    union { u32 i; float f; } v; v.i = ((u32)u) << 16; return v.f;
}
__device__ __forceinline__ u16 f2bf(float f) {
    u32 x = __float_as_uint(f);
    u32 r = (x + 0x7fffu + ((x >> 16) & 1u)) >> 16;
    return (u16)r;
}

// async global->LDS, 16B per lane; dest = wave-uniform base + lane*16
__device__ __forceinline__ void gl16(const void* g, void* lds) {
    __builtin_amdgcn_global_load_lds(
        (const __attribute__((address_space(1))) void*)g,
        (__attribute__((address_space(3))) void*)lds, 16, 0, 0);
}

__device__ __forceinline__ int alibi_w1(int h) {
    // W1 = floor(36 * 2^((h+1)/2) / 64) + 2 ; beyond this many 64-tiles the
    // ALiBi bias alone makes contributions < e^-36 relative (exact drop).
    return (int)(36.0f * exp2f(0.5f * (float)(h + 1)) * (1.0f / 64.0f)) + 2;
}

// ---------------------------------------------------------------------------
__global__ void reset_u32(u32* p, u32 v) { *p = v; }

// ---------------------------------------------------------------------------
__global__ void cvt_f32_bf16(const float* __restrict__ in, u16* __restrict__ out, int nq)
{
    int i = blockIdx.x * blockDim.x + threadIdx.x;
    const int stride = gridDim.x * blockDim.x;
    for (; i < nq; i += stride) {
        f32x4 v = ((const f32x4*)in)[i];
        u16x4 o = { f2bf(v[0]), f2bf(v[1]), f2bf(v[2]), f2bf(v[3]) };
        ((u16x4*)out)[i] = o;
    }
}

// ---------------------------------------------------------------------------
// GEMM (unchanged): 128x128 tile, BK=64, global_load_lds staging.
// ---------------------------------------------------------------------------
template <int EPI>
__global__ __launch_bounds__(256, 3)
void gemm_bt(const u16* __restrict__ A, const u16* __restrict__ Bw,
             const float* __restrict__ bias, u16* __restrict__ C,
             float* __restrict__ Cf, u16* __restrict__ Vt, int M, int N, int K)
{
    __shared__ __align__(16) u16 As[128 * 64];
    __shared__ __align__(16) u16 Bs[128 * 64];

    const int tid = threadIdx.x;
    const int l = tid & 63;
    const int w = tid >> 6;
    const int wr = w >> 1, wc = w & 1;
    const int bm = blockIdx.x, bn = blockIdx.y;

    const int lrow = l >> 3;
    const int lsl  = (l & 7) ^ lrow;
    const size_t aBase = (size_t)(bm * 128 + w * 8 + lrow) * K + lsl * 8;
    const size_t bBase = (size_t)(bn * 128 + w * 8 + lrow) * K + lsl * 8;

    const int sw = (l & 7) << 4;
    int offA[4], offB[4];
#pragma unroll
    for (int mf = 0; mf < 4; ++mf)
        offA[mf] = (wr * 64 + mf * 16 + (l & 15)) * 128 + (((l >> 4) * 16) ^ sw);
#pragma unroll
    for (int nf = 0; nf < 4; ++nf)
        offB[nf] = (wc * 64 + nf * 16 + (l & 15)) * 128 + (((l >> 4) * 16) ^ sw);

    f32x4 acc[4][4];
#pragma unroll
    for (int i = 0; i < 4; ++i)
#pragma unroll
        for (int j = 0; j < 4; ++j)
            acc[i][j] = (f32x4){0.f, 0.f, 0.f, 0.f};

    const int nK = K >> 6;
    for (int kt = 0; kt < nK; ++kt) {
        __syncthreads();
#pragma unroll
        for (int j = 0; j < 4; ++j) {
            gl16(A  + aBase + (size_t)j * 32 * K + kt * 64,
                 (char*)As + (w * 8 + j * 32) * 128);
            gl16(Bw + bBase + (size_t)j * 32 * K + kt * 64,
                 (char*)Bs + (w * 8 + j * 32) * 128);
        }
        __syncthreads();
#pragma unroll
        for (int kk = 0; kk < 2; ++kk) {
            bf16x8 af[4], bfr[4];
#pragma unroll
            for (int mf = 0; mf < 4; ++mf)
                af[mf] = *(const bf16x8*)((const char*)As + (offA[mf] ^ (kk << 6)));
#pragma unroll
            for (int nf = 0; nf < 4; ++nf)
                bfr[nf] = *(const bf16x8*)((const char*)Bs + (offB[nf] ^ (kk << 6)));
            __builtin_amdgcn_s_setprio(1);
#pragma unroll
            for (int mf = 0; mf < 4; ++mf)
#pragma unroll
                for (int nf = 0; nf < 4; ++nf)
                    acc[mf][nf] = __builtin_amdgcn_mfma_f32_16x16x32_bf16(
                        af[mf], bfr[nf], acc[mf][nf], 0, 0, 0);
            __builtin_amdgcn_s_setprio(0);
        }
    }

    const int row0 = bm * 128 + wr * 64 + ((l >> 4) << 2);
    const int col0 = bn * 128 + wc * 64 + (l & 15);
#pragma unroll
    for (int mf = 0; mf < 4; ++mf) {
#pragma unroll
        for (int nf = 0; nf < 4; ++nf) {
            const int row = row0 + mf * 16;
            const int col = col0 + nf * 16;
            const float bv = bias[col];
            float v0 = acc[mf][nf][0] + bv;
            float v1 = acc[mf][nf][1] + bv;
            float v2 = acc[mf][nf][2] + bv;
            float v3 = acc[mf][nf][3] + bv;
            if (EPI == 0) {
                if (col < 2560) {
                    C[(size_t)(row + 0) * QKV_N + col] = f2bf(v0);
                    C[(size_t)(row + 1) * QKV_N + col] = f2bf(v1);
                    C[(size_t)(row + 2) * QKV_N + col] = f2bf(v2);
                    C[(size_t)(row + 3) * QKV_N + col] = f2bf(v3);
                } else {
                    const int dd = col - 2560;
                    const int kv = dd >> 7;
                    const int d = dd & 127;
                    const int bidx = row >> 11;
                    const int tt = row & 2047;
                    u16x4 pv = {f2bf(v0), f2bf(v1), f2bf(v2), f2bf(v3)};
                    *(u16x4*)(Vt + ((size_t)((bidx * KVHEADS + kv) * HD + d)) * T_SEQ + tt) = pv;
                }
            } else {
                Cf[(size_t)(row + 0) * DM + col] = v0;
                Cf[(size_t)(row + 1) * DM + col] = v1;
                Cf[(size_t)(row + 2) * DM + col] = v2;
                Cf[(size_t)(row + 3) * DM + col] = v3;
            }
        }
    }
}

// ---------------------------------------------------------------------------
// Flash attention v8b: r8 structure (QBLK=64) with gl16 single-barrier dbuf.
// Per iter: barrier (drains prior gl16 -> buf[c] staged; prior readers of
// buf[c^1] done) -> issue gl16 tile c+1 into buf[c^1] -> compute buf[c].
// K map: chunk c=w+4j = 4 rows x 256B; lane -> (row l>>4, slot l&15);
//        src row 4w+16j+(l>>4), src slot (l&15)^(4(w&1)|(l>>4)).
// V map (r10 bug fixed): chunk c=w+4j = 8 rows x 128B; lane -> (row l>>3,
//        slot l&7); src d-row 8w+32j+(l>>3), src s-slot (l&7)^(l>>3).
// Both produce LDS content identical to r8's publish layout (read offsets
// unchanged). Work queue / split-K / window / defer-max / ones-MFMA as r8.
// ---------------------------------------------------------------------------
#define PWS_SEG 8448
__global__ __launch_bounds__(256, 2)
void attn_fwd(const u16* __restrict__ qkv, const u16* __restrict__ Vt,
              u16* __restrict__ AO, u32* __restrict__ ctr,
              float* __restrict__ PWS)
{
    __shared__ __align__(16) u16 Ks[2 * 64 * 128];   // 2 x 16KB
    __shared__ __align__(16) u16 Vs[2 * 64 * 128];   // 2 x 16KB [d][s]
    __shared__ __align__(16) u16 Ps[4 * 16 * 64];    // per-wave P, 8KB
    __shared__ int sh_item;

    const int tid = threadIdx.x;
    const int l = tid & 63;
    const int w = tid >> 6;

    const int sw = (l & 7) << 4;
    int offK0[4];
#pragma unroll
    for (int nf = 0; nf < 4; ++nf)
        offK0[nf] = (nf * 16 + (l & 15)) * 256 + (((l >> 4) * 16) ^ sw);

    // gl16 staging maps (dest = wave-uniform base + lane*16)
    const int ldChunk = w * 1024;                               // + j*4096
    const int kslot = ((l & 15) ^ ((4 * (w & 1)) | (l >> 4))) * 8;  // K src slot
    const int vslot = ((l & 7) ^ (l >> 3)) * 8;                     // V src s-slot

    const float LOG2E = 1.4426950408889634f;
    const float scale2 = 0.08838834764831845f * LOG2E;
    const bf16x8 ones = {(short)0x3F80, (short)0x3F80, (short)0x3F80, (short)0x3F80,
                         (short)0x3F80, (short)0x3F80, (short)0x3F80, (short)0x3F80};

    int item = blockIdx.x;   // static first item

    for (;;) {
        __syncthreads();     // prior item's LDS reads done; sh_item reusable
        if (item < 0 && tid == 0) sh_item = (int)atomicAdd(ctr, 1u);
        __syncthreads();
        if (item < 0) item = sh_item;
        if (item >= 1536) break;

        int seg, qt, bh;
        if (item < 512)       { seg = 0; qt = 31 - (item >> 5);          bh = item & 31; }
        else if (item < 1024) { seg = 1; qt = 31 - ((item - 512) >> 5);  bh = item & 31; }
        else                  { seg = 0; qt = 15 - ((item - 1024) >> 5); bh = item & 31; }
        const int b = bh >> 4;
        const int h = bh & 15;
        const int kvh = h >> 2;
        const int q0 = qt << 6;

        const float slope2 = exp2f(-0.5f * (float)(h + 1)) * LOG2E;
        const int W1 = alibi_w1(h);
        const int jt_min = (qt - W1 > 0) ? (qt - W1) : 0;
        const bool split = (qt >= 16) && (W1 >= 16);
        if (seg == 1 && !split) { item = -1; continue; }

        const int jt_hi = seg ? (qt - 16) : qt;
        const int jt_lo = seg ? jt_min : (split ? (qt - 15) : jt_min);

        // per-item staging bases
        const size_t gK0 = (size_t)(b * T_SEQ + 4 * w + (l >> 4)) * QKV_N
                           + 2048 + kvh * HD + kslot;
        const size_t gV0 = (size_t)((b * KVHEADS + kvh) * HD + 8 * w + (l >> 3)) * T_SEQ
                           + vslot;

        // Q fragments in registers
        const size_t qrow_off = (size_t)h * HD + ((l >> 4) << 3);
        bf16x8 qreg[4];
#pragma unroll
        for (int kk = 0; kk < 4; ++kk)
            qreg[kk] = *(const bf16x8*)(qkv +
                (size_t)(b * T_SEQ + q0 + w * 16 + (l & 15)) * QKV_N + qrow_off + kk * 32);

        float m_run[4];
        f32x4 o[8];
        f32x4 lacc = (f32x4){0.f, 0.f, 0.f, 0.f};
#pragma unroll
        for (int i = 0; i < 4; ++i) m_run[i] = -1e30f;
#pragma unroll
        for (int nf = 0; nf < 8; ++nf) o[nf] = (f32x4){0.f, 0.f, 0.f, 0.f};

        // alibi base: abase[nf][i] = slope2*(scol - trow) at jt = jt_hi
        const int tb = q0 + w * 16 + ((l >> 4) << 2);
        const float dslope = slope2 * 64.0f;
        float abase[4][4];
#pragma unroll
        for (int nf = 0; nf < 4; ++nf)
#pragma unroll
            for (int i = 0; i < 4; ++i)
                abase[nf][i] = slope2 * (float)((jt_hi << 6) + nf * 16 + (l & 15) - (tb + i));

        // prologue: issue gl16 for tile jt_hi into buffer 0
#pragma unroll
        for (int j = 0; j < 4; ++j) {
            gl16(qkv + gK0 + (size_t)((jt_hi << 6) + 16 * j) * QKV_N,
                 (char*)Ks + ldChunk + j * 4096);
            gl16(Vt + gV0 + (size_t)(32 * j) * T_SEQ + (jt_hi << 6),
                 (char*)Vs + ldChunk + j * 4096);
        }

        for (int c = 0, jt = jt_hi; jt >= jt_lo; --jt, ++c) {
            const int bsel = (c & 1) << 14;

            __syncthreads();   // drains gl16 -> buf[c&1] staged; buf[c^1] readers done

            // ---- issue gl16 for tile jt-1 into the other buffer ----
            if (jt > jt_lo) {
                const int ns0 = (jt - 1) << 6;
                const int b2 = ((c + 1) & 1) << 14;
#pragma unroll
                for (int j = 0; j < 4; ++j) {
                    gl16(qkv + gK0 + (size_t)(ns0 + 16 * j) * QKV_N,
                         (char*)Ks + b2 + ldChunk + j * 4096);
                    gl16(Vt + gV0 + (size_t)(32 * j) * T_SEQ + ns0,
                         (char*)Vs + b2 + ldChunk + j * 4096);
                }
            }

            // ---- S = Q K^T ----
            f32x4 sc[4];
#pragma unroll
            for (int nf = 0; nf < 4; ++nf) sc[nf] = (f32x4){0.f, 0.f, 0.f, 0.f};
            __builtin_amdgcn_s_setprio(1);
#pragma unroll
            for (int kk = 0; kk < 4; ++kk) {
#pragma unroll
                for (int nf = 0; nf < 4; ++nf) {
                    bf16x8 kb = *(const bf16x8*)((const char*)Ks + bsel + (offK0[nf] ^ (kk << 6)));
                    sc[nf] = __builtin_amdgcn_mfma_f32_16x16x32_bf16(qreg[kk], kb, sc[nf], 0, 0, 0);
                }
            }
            __builtin_amdgcn_s_setprio(0);

            // ---- vals = sc*scale2 + abase (log2 domain) ----
            float vals[4][4];
#pragma unroll
            for (int nf = 0; nf < 4; ++nf)
#pragma unroll
                for (int i = 0; i < 4; ++i) {
                    vals[nf][i] = fmaf(sc[nf][i], scale2, abase[nf][i]);
                    abase[nf][i] -= dslope;
                }
            if (seg == 0 && c == 0) {   // diagonal tile: causal mask
                const int s0 = jt << 6;
#pragma unroll
                for (int nf = 0; nf < 4; ++nf) {
                    const int scol = s0 + nf * 16 + (l & 15);
#pragma unroll
                    for (int i = 0; i < 4; ++i)
                        if (scol > tb + i) vals[nf][i] = -__builtin_inff();
                }
            }

            // ---- shuffle-free defer-max check ----
            float lm[4];
#pragma unroll
            for (int i = 0; i < 4; ++i)
                lm[i] = fmaxf(fmaxf(vals[0][i], vals[1][i]), fmaxf(vals[2][i], vals[3][i]));
            const bool ok = (lm[0] <= m_run[0] + 10.f) && (lm[1] <= m_run[1] + 10.f) &&
                            (lm[2] <= m_run[2] + 10.f) && (lm[3] <= m_run[3] + 10.f);
            if (!__all(ok)) {
                float corr[4];
#pragma unroll
                for (int i = 0; i < 4; ++i) {
                    float mx = lm[i];
#pragma unroll
                    for (int d = 1; d < 16; d <<= 1) mx = fmaxf(mx, __shfl_xor(mx, d, 64));
                    const float mn = fmaxf(m_run[i], mx);
                    corr[i] = exp2f(m_run[i] - mn);
                    m_run[i] = mn;
                }
#pragma unroll
                for (int nf = 0; nf < 8; ++nf) {
                    o[nf][0] *= corr[0]; o[nf][1] *= corr[1];
                    o[nf][2] *= corr[2]; o[nf][3] *= corr[3];
                }
                lacc[0] *= corr[0]; lacc[1] *= corr[1];
                lacc[2] *= corr[2]; lacc[3] *= corr[3];
            }

            // ---- P = exp2(vals - m) -> per-wave LDS (bf16, swizzled) ----
            const int pbase = w * 2048;
#pragma unroll
            for (int nf = 0; nf < 4; ++nf)
#pragma unroll
                for (int i = 0; i < 4; ++i) {
                    const float p = exp2f(vals[nf][i] - m_run[i]);
                    const int r = ((l >> 4) << 2) + i;
                    const int off = pbase + ((r * 128 + nf * 32 + ((l & 15) << 1)) ^ ((r & 7) << 4));
                    *(u16*)((char*)Ps + off) = f2bf(p);
                }

            // ---- O += P @ V ; lacc += P @ ones (row-sums) ----
            const int rp = l & 15;
            __builtin_amdgcn_s_setprio(1);
#pragma unroll
            for (int kk = 0; kk < 2; ++kk) {
                bf16x8 pfr = *(const bf16x8*)((const char*)Ps + pbase +
                              (rp * 128 + ((((l >> 4) * 16) ^ sw) ^ (kk << 6))));
                lacc = __builtin_amdgcn_mfma_f32_16x16x32_bf16(pfr, ones, lacc, 0, 0, 0);
#pragma unroll
                for (int nf = 0; nf < 8; ++nf) {
                    const int offv = (nf * 16 + (l & 15)) * 128 + ((((l >> 4) * 16) ^ sw) ^ (kk << 6));
                    bf16x8 vb = *(const bf16x8*)((const char*)Vs + bsel + offv);
                    o[nf] = __builtin_amdgcn_mfma_f32_16x16x32_bf16(pfr, vb, o[nf], 0, 0, 0);
                }
            }
            __builtin_amdgcn_s_setprio(0);
        }

        // ---- epilogue ----
        if (!split) {
            float rinv[4];
#pragma unroll
            for (int i = 0; i < 4; ++i) rinv[i] = 1.f / lacc[i];
            const size_t orow = (size_t)(b * T_SEQ + q0 + w * 16 + ((l >> 4) << 2));
#pragma unroll
            for (int nf = 0; nf < 8; ++nf) {
                const int col = h * HD + nf * 16 + (l & 15);
#pragma unroll
                for (int i = 0; i < 4; ++i)
                    AO[(orow + i) * DM + col] = f2bf(o[nf][i] * rinv[i]);
            }
        } else {
            const int rid = (bh << 5) | qt;
            float* base = PWS + (size_t)(rid * 2 + seg) * PWS_SEG;
            const int row0 = w * 16 + ((l >> 4) << 2);
#pragma unroll
            for (int nf = 0; nf < 8; ++nf) {
                const int col = nf * 16 + (l & 15);
#pragma unroll
                for (int i = 0; i < 4; ++i)
                    base[(row0 + i) * 128 + col] = o[nf][i];
            }
            if ((l & 15) == 0) {
#pragma unroll
                for (int i = 0; i < 4; ++i) {
                    base[8192 + row0 + i] = m_run[i];
                    base[8256 + row0 + i] = lacc[i];
                }
            }
        }

        item = -1;   // pop next from queue
    }
}

// ---------------------------------------------------------------------------
// Combine split items: AO[row] = (O0*w0 + O1*w1) / (l0*w0 + l1*w1)
// ---------------------------------------------------------------------------
__global__ __launch_bounds__(256)
void attn_combine(const float* __restrict__ PWS, u16* __restrict__ AO)
{
    const int rid = blockIdx.x;          // (bh<<5)|qt
    const int qt = rid & 31;
    const int bh = rid >> 5;
    const int b = bh >> 4;
    const int h = bh & 15;
    if (!(qt >= 16 && alibi_w1(h) >= 16)) return;

    const float* p0 = PWS + (size_t)(rid * 2 + 0) * PWS_SEG;
    const float* p1 = PWS + (size_t)(rid * 2 + 1) * PWS_SEG;

    const int t = threadIdx.x;
    const int row = t >> 2;
    const int c0 = (t & 3) * 32;

    const float m0 = p0[8192 + row], m1 = p1[8192 + row];
    const float l0 = p0[8256 + row], l1 = p1[8256 + row];
    const float m = fmaxf(m0, m1);
    const float w0 = exp2f(m0 - m), w1 = exp2f(m1 - m);
    const float rinv = 1.f / (l0 * w0 + l1 * w1);

    const size_t ao = (size_t)(b * T_SEQ + (qt << 6) + row) * DM + h * HD + c0;
#pragma unroll
    for (int j = 0; j < 32; ++j) {
        const float v = (p0[row * 128 + c0 + j] * w0 + p1[row * 128 + c0 + j] * w1) * rinv;
        AO[ao + j] = f2bf(v);
    }
}

// ---------------------------------------------------------------------------
extern "C" void kernel_launch(void* const* d_in, const int* in_sizes, int n_in,
                              void* d_out, int out_size, void* d_ws, size_t ws_size,
                              hipStream_t stream)
{
    const float* x      = (const float*)d_in[0];
    // d_in[1] = attn_mask (causal, analytic)
    // d_in[2] = alibi_bias (analytic)
    const float* qkv_w  = (const float*)d_in[3];
    const float* qkv_b  = (const float*)d_in[4];
    const float* proj_w = (const float*)d_in[5];
    const float* proj_b = (const float*)d_in[6];
    float* out = (float*)d_out;

    u16* ws  = (u16*)d_ws;
    u16* xb  = ws;                                   // 4096*2048
    u16* AO  = ws;                                   // alias: x dead after gemm0
    u16* qwb = ws + 8388608;                         // 3072*2048
    u16* pwb = qwb + 6291456;                        // 2048*2048
    u16* qkv = pwb + 4194304;                        // 4096*3072
    u16* Vt  = qkv + 12582912;                       // 2*4*128*2048
    u32* ctr = (u32*)(ws + 33554432);                // queue counter (4B)
    float* PWS = (float*)((char*)d_ws + 67108880);   // split partials ~69MB

    reset_u32<<<1, 1, 0, stream>>>(ctr, 512u);
    cvt_f32_bf16<<<2048, 256, 0, stream>>>(x,      xb,  8388608 / 4);
    cvt_f32_bf16<<<2048, 256, 0, stream>>>(qkv_w,  qwb, 6291456 / 4);
    cvt_f32_bf16<<<1024, 256, 0, stream>>>(proj_w, pwb, 4194304 / 4);

    gemm_bt<0><<<dim3(32, 24), 256, 0, stream>>>(xb, qwb, qkv_b, qkv, nullptr, Vt,
                                                 MROWS, QKV_N, DM);
    attn_fwd<<<dim3(512), 256, 0, stream>>>(qkv, Vt, AO, ctr, PWS);
    attn_combine<<<dim3(1024), 256, 0, stream>>>(PWS, AO);
    gemm_bt<1><<<dim3(32, 16), 256, 0, stream>>>(AO, pwb, proj_b, nullptr, out, nullptr,
                                                 MROWS, DM, DM);
}